// Round 4
// baseline (231.421 us; speedup 1.0000x reference)
//
#include <hip/hip_runtime.h>
#include <math.h>

#define H 256

// Stage 1: W[r][c] = sum_{l: loc(l)=r} w_c(l)   (scatter-add, 1.6 MB, L2-resident)
// w0=beta*alpha, w1=beta*(1-alpha), w2=(1-beta)*alpha, w3=(1-beta)*(1-alpha)
__global__ __launch_bounds__(256) void strnn_scatter(
    const float* __restrict__ td_u, const float* __restrict__ td_l,
    const float* __restrict__ ld_u, const float* __restrict__ ld_l,
    const int* __restrict__ loc, float* __restrict__ W, int L)
{
    const int i = blockIdx.x * 256 + threadIdx.x;
    if (i >= L) return;
    float tu = fminf(fmaxf(td_u[i], 0.f), 1440.f);
    float tl = fminf(fmaxf(td_l[i], 0.f), 1440.f);
    float lu = fminf(fmaxf(ld_u[i], 0.f), 40.f);
    float ll = fminf(fmaxf(ld_l[i], 0.f), 40.f);
    float al = tu / (tu + tl);
    float be = lu / (lu + ll);
    float* w = W + 4 * (size_t)loc[i];
    atomicAdd(w + 0, be * al);
    atomicAdd(w + 1, be * (1.f - al));
    atomicAdd(w + 2, (1.f - be) * al);
    atomicAdd(w + 3, (1.f - be) * (1.f - al));
}

// Stage 2: v[c][h] = sum_r W[r][c] * table[r][h] — LINEAR stream of the table.
// Row-per-wave, 8 contiguous rows (8 KB) in flight per wave. Unreferenced rows
// (sum_c W[r][c] == 0, exact: the sum equals the reference count) have their
// load redirected to row 0 (L1-hit) — saves ~27% of HBM fetch, no branches.
__global__ __launch_bounds__(256) void strnn_stream(
    const float* __restrict__ table, const float* __restrict__ W,
    float* __restrict__ v, int R)
{
    __shared__ float s_red[4][4][H];  // 16 KB: [wave][c][col]
    const int t    = threadIdx.x;
    const int wave = t >> 6;
    const int lane = t & 63;
    const int gw   = blockIdx.x * 4 + wave;
    const int nw   = gridDim.x * 4;

    float4 a0 = {0,0,0,0}, a1 = {0,0,0,0}, a2 = {0,0,0,0}, a3 = {0,0,0,0};

    for (int base = gw * 8; base + 8 <= R; base += nw * 8) {
        float4 w[8];
        #pragma unroll
        for (int u = 0; u < 8; ++u)
            w[u] = *(const float4*)(W + 4 * (size_t)(base + u));
        int ra[8];
        #pragma unroll
        for (int u = 0; u < 8; ++u) {
            float sw = (w[u].x + w[u].y) + (w[u].z + w[u].w);
            ra[u] = (sw != 0.f) ? (base + u) : 0;   // dead row -> row 0 (cached)
        }
        float4 e[8];
        #pragma unroll
        for (int u = 0; u < 8; ++u)
            e[u] = *(const float4*)(table + (size_t)ra[u] * H + 4 * lane);
        #pragma unroll
        for (int u = 0; u < 8; ++u) {
            a0.x = fmaf(w[u].x, e[u].x, a0.x);
            a0.y = fmaf(w[u].x, e[u].y, a0.y);
            a0.z = fmaf(w[u].x, e[u].z, a0.z);
            a0.w = fmaf(w[u].x, e[u].w, a0.w);
            a1.x = fmaf(w[u].y, e[u].x, a1.x);
            a1.y = fmaf(w[u].y, e[u].y, a1.y);
            a1.z = fmaf(w[u].y, e[u].z, a1.z);
            a1.w = fmaf(w[u].y, e[u].w, a1.w);
            a2.x = fmaf(w[u].z, e[u].x, a2.x);
            a2.y = fmaf(w[u].z, e[u].y, a2.y);
            a2.z = fmaf(w[u].z, e[u].z, a2.z);
            a2.w = fmaf(w[u].z, e[u].w, a2.w);
            a3.x = fmaf(w[u].w, e[u].x, a3.x);
            a3.y = fmaf(w[u].w, e[u].y, a3.y);
            a3.z = fmaf(w[u].w, e[u].z, a3.z);
            a3.w = fmaf(w[u].w, e[u].w, a3.w);
        }
    }
    // tail rows (R % 8 != 0): wave 0 of block 0 handles them
    if (gw == 0) {
        for (int r = R & ~7; r < R; ++r) {
            float4 w = *(const float4*)(W + 4 * (size_t)r);
            float4 e = *(const float4*)(table + (size_t)r * H + 4 * lane);
            a0.x = fmaf(w.x, e.x, a0.x); a0.y = fmaf(w.x, e.y, a0.y);
            a0.z = fmaf(w.x, e.z, a0.z); a0.w = fmaf(w.x, e.w, a0.w);
            a1.x = fmaf(w.y, e.x, a1.x); a1.y = fmaf(w.y, e.y, a1.y);
            a1.z = fmaf(w.y, e.z, a1.z); a1.w = fmaf(w.y, e.w, a1.w);
            a2.x = fmaf(w.z, e.x, a2.x); a2.y = fmaf(w.z, e.y, a2.y);
            a2.z = fmaf(w.z, e.z, a2.z); a2.w = fmaf(w.z, e.w, a2.w);
            a3.x = fmaf(w.w, e.x, a3.x); a3.y = fmaf(w.w, e.y, a3.y);
            a3.z = fmaf(w.w, e.z, a3.z); a3.w = fmaf(w.w, e.w, a3.w);
        }
    }

    // cross-wave block reduction, then 4 atomicAdds per thread
    *(float4*)&s_red[wave][0][4 * lane] = a0;
    *(float4*)&s_red[wave][1][4 * lane] = a1;
    *(float4*)&s_red[wave][2][4 * lane] = a2;
    *(float4*)&s_red[wave][3][4 * lane] = a3;
    __syncthreads();
    #pragma unroll
    for (int c = 0; c < 4; ++c) {
        float s = s_red[0][c][t] + s_red[1][c][t] + s_red[2][c][t] + s_red[3][c][t];
        atomicAdd(&v[c * H + t], s);
    }
}

// Kernel 2a: one wave per output row h:
//   p[h] = Wtu[h,:]·v1 + Wtl[h,:]·v2 ; q[h] = Wtu[h,:]·v3 + Wtl[h,:]·v4 ; u[h] = Wih[h,:]·hx
__global__ __launch_bounds__(256) void strnn_mid(
    const float* __restrict__ Wtu, const float* __restrict__ Wtl,
    const float* __restrict__ Wih, const float* __restrict__ hx,
    const float* __restrict__ v, float* __restrict__ pqu)
{
    const int wave = (blockIdx.x * blockDim.x + threadIdx.x) >> 6;  // = h
    const int lane = threadIdx.x & 63;
    const float* v1 = v;
    const float* v2 = v + H;
    const float* v3 = v + 2 * H;
    const float* v4 = v + 3 * H;

    float p = 0.f, q = 0.f, u = 0.f;
    #pragma unroll
    for (int i = 0; i < H; i += 64) {
        const int k = i + lane;
        const float wtu = Wtu[wave * H + k];
        const float wtl = Wtl[wave * H + k];
        p = fmaf(wtu, v1[k], fmaf(wtl, v2[k], p));
        q = fmaf(wtu, v3[k], fmaf(wtl, v4[k], q));
        u = fmaf(Wih[wave * H + k], hx[k], u);
    }
    #pragma unroll
    for (int off = 32; off > 0; off >>= 1) {
        p += __shfl_down(p, off, 64);
        q += __shfl_down(q, off, 64);
        u += __shfl_down(u, off, 64);
    }
    if (lane == 0) {
        pqu[wave]         = p;
        pqu[H + wave]     = q;
        pqu[2 * H + wave] = u;
    }
}

// Kernel 2b: out[h] = sigmoid( Wsu[h,:]·p + Wsl[h,:]·q + u[h] )
__global__ __launch_bounds__(256) void strnn_out(
    const float* __restrict__ Wsu, const float* __restrict__ Wsl,
    const float* __restrict__ pqu, float* __restrict__ out)
{
    const int wave = (blockIdx.x * blockDim.x + threadIdx.x) >> 6;  // = h
    const int lane = threadIdx.x & 63;
    const float* p = pqu;
    const float* q = pqu + H;
    const float* u = pqu + 2 * H;

    float s = 0.f;
    #pragma unroll
    for (int i = 0; i < H; i += 64) {
        const int k = i + lane;
        s = fmaf(Wsu[wave * H + k], p[k], fmaf(Wsl[wave * H + k], q[k], s));
    }
    #pragma unroll
    for (int off = 32; off > 0; off >>= 1)
        s += __shfl_down(s, off, 64);
    if (lane == 0)
        out[wave] = 1.f / (1.f + expf(-(s + u[wave])));
}

extern "C" void kernel_launch(void* const* d_in, const int* in_sizes, int n_in,
                              void* d_out, int out_size, void* d_ws, size_t ws_size,
                              hipStream_t stream) {
    const float* td_u  = (const float*)d_in[0];
    const float* td_l  = (const float*)d_in[1];
    const float* ld_u  = (const float*)d_in[2];
    const float* ld_l  = (const float*)d_in[3];
    const int*   loc   = (const int*)d_in[4];
    const float* hx    = (const float*)d_in[5];
    const float* Wih   = (const float*)d_in[6];
    const float* Wtu   = (const float*)d_in[7];
    const float* Wtl   = (const float*)d_in[8];
    const float* Wsu   = (const float*)d_in[9];
    const float* Wsl   = (const float*)d_in[10];
    const float* table = (const float*)d_in[11];
    const int L = in_sizes[0];
    const int R = in_sizes[11] / H;   // LOC_CNT

    float* W   = (float*)d_ws;        // 4*R weight histogram (1.6 MB)
    float* v   = W + 4 * (size_t)R;   // 4*H accumulators
    float* pqu = v + 4 * H;           // p, q, usr (3*H)

    // ws is re-poisoned to 0xAA before every launch — zero W and v together.
    hipMemsetAsync(W, 0, (4 * (size_t)R + 4 * H) * sizeof(float), stream);

    strnn_scatter<<<(L + 255) / 256, 256, 0, stream>>>(td_u, td_l, ld_u, ld_l, loc, W, L);
    strnn_stream<<<256, 256, 0, stream>>>(table, W, v, R);
    strnn_mid<<<64, 256, 0, stream>>>(Wtu, Wtl, Wih, hx, v, pqu);
    strnn_out<<<64, 256, 0, stream>>>(Wsu, Wsl, pqu, (float*)d_out);
}

// Round 5
// 185.174 us; speedup vs baseline: 1.2497x; 1.2497x over previous
//
#include <hip/hip_runtime.h>
#include <math.h>

#define H 256
#define TILE 256

// Kernel 1: v[c][h] = sum_l w_c(l) * table[loc[l]][h], c = 0..3
// w0=beta*alpha, w1=beta*(1-alpha), w2=(1-beta)*alpha, w3=(1-beta)*(1-alpha)
// alpha = tu/(tu+tl), beta = lu/(lu+ll) after clipping.
//
// Row-per-wave: wave w owns 64 rows of the block's 256-row tile; one
// global_load_dwordx4 per lane covers a full 1 KB table row per wave
// instruction. Software-pipelined double-buffered row loads: 16 rows
// (16 KB/wave, 128 KB/CU at 8 waves/CU) in flight at all times, so the
// compiler waits at vmcnt(8) instead of draining each batch. Weights
// broadcast from LDS as float4. Cross-wave LDS reduction, then 4
// atomicAdds per thread (512 adds/address total).
__global__ __launch_bounds__(256) void strnn_gather(
    const float* __restrict__ td_u, const float* __restrict__ td_l,
    const float* __restrict__ ld_u, const float* __restrict__ ld_l,
    const int* __restrict__ loc, const float* __restrict__ table,
    float* __restrict__ v, int L)
{
    __shared__ float4 s_w[TILE];       //  4 KB
    __shared__ int    s_loc[TILE];     //  1 KB
    __shared__ float  s_red[4][4][H];  // 16 KB: [wave][c][col]
    const int t    = threadIdx.x;
    const int wave = t >> 6;
    const int lane = t & 63;

    float4 a0 = {0,0,0,0}, a1 = {0,0,0,0}, a2 = {0,0,0,0}, a3 = {0,0,0,0};

    for (int base = blockIdx.x * TILE; base < L; base += gridDim.x * TILE) {
        const int l = base + t;
        const bool ok = (l < L);
        float tu = ok ? fminf(fmaxf(td_u[l], 0.f), 1440.f) : 1.f;
        float tl = ok ? fminf(fmaxf(td_l[l], 0.f), 1440.f) : 1.f;
        float lu = ok ? fminf(fmaxf(ld_u[l], 0.f), 40.f)   : 1.f;
        float ll = ok ? fminf(fmaxf(ld_l[l], 0.f), 40.f)   : 1.f;
        float al = tu / (tu + tl);
        float be = lu / (lu + ll);
        float w0 = be * al, w1 = be * (1.f - al);
        float w2 = (1.f - be) * al, w3 = (1.f - be) * (1.f - al);
        if (!ok) { w0 = w1 = w2 = w3 = 0.f; }
        s_w[t]   = make_float4(w0, w1, w2, w3);
        s_loc[t] = ok ? loc[l] : 0;
        __syncthreads();

        const int r0 = wave * 64;
        float4 e0[8], e1[8];

        // prologue: batch 0 in flight
        #pragma unroll
        for (int u = 0; u < 8; ++u)
            e0[u] = *(const float4*)(table + (size_t)s_loc[r0 + u] * H + 4 * lane);

        #pragma unroll
        for (int j = 0; j < 64; j += 16) {
            // issue batch j+8 while batch j is outstanding
            #pragma unroll
            for (int u = 0; u < 8; ++u)
                e1[u] = *(const float4*)(table + (size_t)s_loc[r0 + j + 8 + u] * H + 4 * lane);
            // consume batch j
            #pragma unroll
            for (int u = 0; u < 8; ++u) {
                const float4 w = s_w[r0 + j + u];
                const float4 e = e0[u];
                a0.x = fmaf(w.x, e.x, a0.x); a0.y = fmaf(w.x, e.y, a0.y);
                a0.z = fmaf(w.x, e.z, a0.z); a0.w = fmaf(w.x, e.w, a0.w);
                a1.x = fmaf(w.y, e.x, a1.x); a1.y = fmaf(w.y, e.y, a1.y);
                a1.z = fmaf(w.y, e.z, a1.z); a1.w = fmaf(w.y, e.w, a1.w);
                a2.x = fmaf(w.z, e.x, a2.x); a2.y = fmaf(w.z, e.y, a2.y);
                a2.z = fmaf(w.z, e.z, a2.z); a2.w = fmaf(w.z, e.w, a2.w);
                a3.x = fmaf(w.w, e.x, a3.x); a3.y = fmaf(w.w, e.y, a3.y);
                a3.z = fmaf(w.w, e.z, a3.z); a3.w = fmaf(w.w, e.w, a3.w);
            }
            // issue batch j+16 (skip on last iteration)
            if (j + 16 < 64) {
                #pragma unroll
                for (int u = 0; u < 8; ++u)
                    e0[u] = *(const float4*)(table + (size_t)s_loc[r0 + j + 16 + u] * H + 4 * lane);
            }
            // consume batch j+8
            #pragma unroll
            for (int u = 0; u < 8; ++u) {
                const float4 w = s_w[r0 + j + 8 + u];
                const float4 e = e1[u];
                a0.x = fmaf(w.x, e.x, a0.x); a0.y = fmaf(w.x, e.y, a0.y);
                a0.z = fmaf(w.x, e.z, a0.z); a0.w = fmaf(w.x, e.w, a0.w);
                a1.x = fmaf(w.y, e.x, a1.x); a1.y = fmaf(w.y, e.y, a1.y);
                a1.z = fmaf(w.y, e.z, a1.z); a1.w = fmaf(w.y, e.w, a1.w);
                a2.x = fmaf(w.z, e.x, a2.x); a2.y = fmaf(w.z, e.y, a2.y);
                a2.z = fmaf(w.z, e.z, a2.z); a2.w = fmaf(w.z, e.w, a2.w);
                a3.x = fmaf(w.w, e.x, a3.x); a3.y = fmaf(w.w, e.y, a3.y);
                a3.z = fmaf(w.w, e.z, a3.z); a3.w = fmaf(w.w, e.w, a3.w);
            }
        }
        __syncthreads();
    }

    // cross-wave block reduction in LDS
    *(float4*)&s_red[wave][0][4 * lane] = a0;
    *(float4*)&s_red[wave][1][4 * lane] = a1;
    *(float4*)&s_red[wave][2][4 * lane] = a2;
    *(float4*)&s_red[wave][3][4 * lane] = a3;
    __syncthreads();
    #pragma unroll
    for (int c = 0; c < 4; ++c) {
        float s = s_red[0][c][t] + s_red[1][c][t] + s_red[2][c][t] + s_red[3][c][t];
        atomicAdd(&v[c * H + t], s);
    }
}

// Kernel 2a: one wave per output row h:
//   p[h] = Wtu[h,:]·v1 + Wtl[h,:]·v2 ; q[h] = Wtu[h,:]·v3 + Wtl[h,:]·v4 ; u[h] = Wih[h,:]·hx
__global__ __launch_bounds__(256) void strnn_mid(
    const float* __restrict__ Wtu, const float* __restrict__ Wtl,
    const float* __restrict__ Wih, const float* __restrict__ hx,
    const float* __restrict__ v, float* __restrict__ pqu)
{
    const int wave = (blockIdx.x * blockDim.x + threadIdx.x) >> 6;  // = h
    const int lane = threadIdx.x & 63;
    const float* v1 = v;
    const float* v2 = v + H;
    const float* v3 = v + 2 * H;
    const float* v4 = v + 3 * H;

    float p = 0.f, q = 0.f, u = 0.f;
    #pragma unroll
    for (int i = 0; i < H; i += 64) {
        const int k = i + lane;
        const float wtu = Wtu[wave * H + k];
        const float wtl = Wtl[wave * H + k];
        p = fmaf(wtu, v1[k], fmaf(wtl, v2[k], p));
        q = fmaf(wtu, v3[k], fmaf(wtl, v4[k], q));
        u = fmaf(Wih[wave * H + k], hx[k], u);
    }
    #pragma unroll
    for (int off = 32; off > 0; off >>= 1) {
        p += __shfl_down(p, off, 64);
        q += __shfl_down(q, off, 64);
        u += __shfl_down(u, off, 64);
    }
    if (lane == 0) {
        pqu[wave]         = p;
        pqu[H + wave]     = q;
        pqu[2 * H + wave] = u;
    }
}

// Kernel 2b: out[h] = sigmoid( Wsu[h,:]·p + Wsl[h,:]·q + u[h] )
__global__ __launch_bounds__(256) void strnn_out(
    const float* __restrict__ Wsu, const float* __restrict__ Wsl,
    const float* __restrict__ pqu, float* __restrict__ out)
{
    const int wave = (blockIdx.x * blockDim.x + threadIdx.x) >> 6;  // = h
    const int lane = threadIdx.x & 63;
    const float* p = pqu;
    const float* q = pqu + H;
    const float* u = pqu + 2 * H;

    float s = 0.f;
    #pragma unroll
    for (int i = 0; i < H; i += 64) {
        const int k = i + lane;
        s = fmaf(Wsu[wave * H + k], p[k], fmaf(Wsl[wave * H + k], q[k], s));
    }
    #pragma unroll
    for (int off = 32; off > 0; off >>= 1)
        s += __shfl_down(s, off, 64);
    if (lane == 0)
        out[wave] = 1.f / (1.f + expf(-(s + u[wave])));
}

extern "C" void kernel_launch(void* const* d_in, const int* in_sizes, int n_in,
                              void* d_out, int out_size, void* d_ws, size_t ws_size,
                              hipStream_t stream) {
    const float* td_u  = (const float*)d_in[0];
    const float* td_l  = (const float*)d_in[1];
    const float* ld_u  = (const float*)d_in[2];
    const float* ld_l  = (const float*)d_in[3];
    const int*   loc   = (const int*)d_in[4];
    const float* hx    = (const float*)d_in[5];
    const float* Wih   = (const float*)d_in[6];
    const float* Wtu   = (const float*)d_in[7];
    const float* Wtl   = (const float*)d_in[8];
    const float* Wsu   = (const float*)d_in[9];
    const float* Wsl   = (const float*)d_in[10];
    const float* table = (const float*)d_in[11];
    const int L = in_sizes[0];

    float* v   = (float*)d_ws;   // 4*H accumulators
    float* pqu = v + 4 * H;      // p, q, usr (3*H)

    // ws is re-poisoned to 0xAA before every launch — zero the accumulators.
    hipMemsetAsync(v, 0, 4 * H * sizeof(float), stream);

    strnn_gather<<<512, 256, 0, stream>>>(td_u, td_l, ld_u, ld_l, loc, table, v, L);
    strnn_mid<<<64, 256, 0, stream>>>(Wtu, Wtl, Wih, hx, v, pqu);
    strnn_out<<<64, 256, 0, stream>>>(Wsu, Wsl, pqu, (float*)d_out);
}